// Round 5
// baseline (119.857 us; speedup 1.0000x reference)
//
#include <hip/hip_runtime.h>
#include <hip/hip_bf16.h>

#define B_ROWS 4096
#define T_LEN  8192
#define N_TAPS 256

typedef __attribute__((ext_vector_type(8))) short short8;
typedef __attribute__((ext_vector_type(4))) short short4v;
typedef __attribute__((ext_vector_type(4))) float f32x4;

__device__ inline ushort f2bf(float f) {
    __hip_bfloat16 h = __float2bfloat16(f);
    union { __hip_bfloat16 h; ushort u; } c;
    c.h = h;
    return c.u;
}

// async global->LDS, 16 B per lane. LDS dest = wave-uniform base + lane*16.
typedef __attribute__((address_space(1))) const void g_void;
typedef __attribute__((address_space(3))) void s_void;
__device__ inline void gload16(const void* g, void* s) {
    __builtin_amdgcn_global_load_lds((g_void*)g, (s_void*)s, 16, 0, 0);
}

// ---------------------------------------------------------------------------
// Phase 0a: cast z (256 x 8192 fp32) -> zbf (bf16)
// ---------------------------------------------------------------------------
__global__ __launch_bounds__(256) void fir_cast_z(const float* __restrict__ z,
                                                  ushort* __restrict__ zbf) {
    const int idx = (blockIdx.x * 256 + threadIdx.x) * 8;
    float4 a = *(const float4*)&z[idx];
    float4 b = *(const float4*)&z[idx + 4];
    short8 o;
    o[0] = (short)f2bf(a.x); o[1] = (short)f2bf(a.y);
    o[2] = (short)f2bf(a.z); o[3] = (short)f2bf(a.w);
    o[4] = (short)f2bf(b.x); o[5] = (short)f2bf(b.y);
    o[6] = (short)f2bf(b.z); o[7] = (short)f2bf(b.w);
    *(short8*)&zbf[idx] = o;
}

// ---------------------------------------------------------------------------
// Phase 0b: Toeplitz B-fragment table (unchanged, verified R3)
// ---------------------------------------------------------------------------
__global__ void fir_build_wtab(const float* __restrict__ b,
                               ushort* __restrict__ wtab) {
    const int a = blockIdx.x;        // 0..21
    const int lane = threadIdx.x;    // 0..63
    const int l15 = lane & 15, lg = lane >> 4;
    short8 o;
    #pragma unroll
    for (int j = 0; j < 8; ++j) {
        const int bi = 16 * a - 32 + l15 - lg * 8 - j;
        const float v = (bi >= 0 && bi < N_TAPS) ? b[bi] : 0.f;
        o[j] = (short)f2bf(v);
    }
    *(short8*)&wtab[(a * 64 + lane) * 8] = o;
}

// ---------------------------------------------------------------------------
// Phase 1: zi GEMM. Occupancy-first geometry: GBK=32 -> LDS 48 KB ->
// 2 blocks/CU resident (16 waves/CU) so inter-block TLP hides latency
// regardless of compiler scheduling. kslices=16 -> 512 blocks = 2/CU.
// B staged by global_load_lds (linear dest, pre-swizzled source);
// A reg-prefetched fp32 -> cvt -> swizzled ds_write. 1 barrier/iter.
// LDS rows are 64 B; swizzle: 16B-slot ^= (row&3).
// ---------------------------------------------------------------------------
#define MT 128
#define GBK 32
#define ASZ (MT * GBK)        // 4096 ushorts = 8 KB
#define BSZ (N_TAPS * GBK)    // 8192 ushorts = 16 KB

__global__ __launch_bounds__(512, 4) void fir_zi_gemm(
        const float* __restrict__ x,
        const ushort* __restrict__ zbf,
        float* __restrict__ part,
        int kslices) {
    __shared__ ushort As[2 * ASZ];   // 16 KB
    __shared__ ushort Bs[2 * BSZ];   // 32 KB
    const int i0 = blockIdx.x * MT;
    const int ks = blockIdx.y;
    const int klen = T_LEN / kslices;
    const int kbase = ks * klen;
    const int tid = threadIdx.x;
    const int wid = tid >> 6, lane = tid & 63;
    const int wm = wid >> 2, wn = wid & 3;
    const int l15 = lane & 15, lg = lane >> 4;

    // A staging coords: round q covers rows (tid>>3) + q*64? No:
    // e = tid + q*512; r = e>>3 in 0..127, c4 = (e&7)*4 in {0..28}
    const int a_r0 = tid >> 3;          // row for q=0 (0..63)
    const int a_c4 = (tid & 7) * 4;     // fp32 col
    // B staging coords: round q covers rows q*128 + wid*16 + (lane>>2)
    const int b_rl = lane >> 2;         // row within wave's 16-row group
    const int b_c  = lane & 3;          // 16B chunk within 64-B row

    f32x4 acc[4][4];
    #pragma unroll
    for (int mi = 0; mi < 4; ++mi)
        #pragma unroll
        for (int ni = 0; ni < 4; ++ni) acc[mi][ni] = (f32x4){0.f, 0.f, 0.f, 0.f};

    const int nt = klen / GBK;

    float4 apf[2];

    auto issueA = [&](int kc) {
        #pragma unroll
        for (int q = 0; q < 2; ++q) {
            const int r = a_r0 + q * 64;
            apf[q] = *(const float4*)&x[(size_t)(i0 + r) * T_LEN + kbase + kc + a_c4];
        }
    };
    auto issueB = [&](int kc, int buf) {
        #pragma unroll
        for (int q = 0; q < 2; ++q) {
            const int row = q * 128 + wid * 16 + b_rl;
            const int gc  = b_c ^ (row & 3);            // pre-swizzled source
            const void* g = &zbf[(size_t)row * T_LEN + kbase + kc + gc * 8];
            void* s = (char*)&Bs[buf * BSZ] + q * 8192 + wid * 1024;  // wave-uniform
            gload16(g, s);
        }
    };
    auto writeA = [&](int buf) {
        #pragma unroll
        for (int q = 0; q < 2; ++q) {
            const int r = a_r0 + q * 64;
            short4v o;
            o[0] = (short)f2bf(apf[q].x); o[1] = (short)f2bf(apf[q].y);
            o[2] = (short)f2bf(apf[q].z); o[3] = (short)f2bf(apf[q].w);
            const int boff = r * 64 + ((a_c4 * 2) ^ ((r & 3) << 4));
            *(short4v*)((char*)&As[buf * ASZ] + boff) = o;
        }
    };

    // ---- prologue: tile 0 into buf 0 ----
    issueA(0);
    issueB(0, 0);
    writeA(0);
    __syncthreads();

    int cur = 0;
    for (int t = 0; t < nt; ++t) {
        const int pf = (t + 1 < nt);
        if (pf) {
            issueA((t + 1) * GBK);
            issueB((t + 1) * GBK, cur ^ 1);
        }
        const char* Ab = (const char*)&As[cur * ASZ];
        const char* Bb = (const char*)&Bs[cur * BSZ];
        short8 af[4], bfr[4];
        const int cb = lg * 16;   // byte col of this lane's k-frag
        #pragma unroll
        for (int mi = 0; mi < 4; ++mi) {
            const int row = wm * 64 + mi * 16 + l15;
            af[mi] = *(const short8*)(Ab + row * 64 + (cb ^ ((row & 3) << 4)));
        }
        #pragma unroll
        for (int ni = 0; ni < 4; ++ni) {
            const int row = wn * 64 + ni * 16 + l15;
            bfr[ni] = *(const short8*)(Bb + row * 64 + (cb ^ ((row & 3) << 4)));
        }
        #pragma unroll
        for (int mi = 0; mi < 4; ++mi)
            #pragma unroll
            for (int ni = 0; ni < 4; ++ni)
                acc[mi][ni] = __builtin_amdgcn_mfma_f32_16x16x32_bf16(
                    af[mi], bfr[ni], acc[mi][ni], 0, 0, 0);
        if (pf) writeA(cur ^ 1);
        __syncthreads();
        cur ^= 1;
    }

    // C/D layout: col = lane&15, row = (lane>>4)*4 + reg
    #pragma unroll
    for (int mi = 0; mi < 4; ++mi) {
        #pragma unroll
        for (int ni = 0; ni < 4; ++ni) {
            const int gn = wn * 64 + ni * 16 + l15;
            #pragma unroll
            for (int rg = 0; rg < 4; ++rg) {
                const int gm = i0 + wm * 64 + mi * 16 + lg * 4 + rg;
                part[((size_t)ks * B_ROWS + gm) * N_TAPS + gn] = acc[mi][ni][rg];
            }
        }
    }
}

// ---------------------------------------------------------------------------
// Phase 2: reduce split-K partials -> zi
// ---------------------------------------------------------------------------
__global__ __launch_bounds__(256) void fir_zi_reduce(const float* __restrict__ part,
                                                     float* __restrict__ zi,
                                                     int kslices) {
    const int idx = blockIdx.x * 256 + threadIdx.x;
    const int total = B_ROWS * N_TAPS / 4;
    if (idx >= total) return;
    float4 s = ((const float4*)part)[idx];
    for (int q = 1; q < kslices; ++q) {
        float4 v = ((const float4*)part)[(size_t)q * total + idx];
        s.x += v.x; s.y += v.y; s.z += v.z; s.w += v.w;
    }
    ((float4*)zi)[idx] = s;
}

// ---------------------------------------------------------------------------
// Phase 3: FIR conv via MFMA (unchanged from R3 — verified)
// ---------------------------------------------------------------------------
#define VBM 16
#define VBT 1024
#define VWIN 1280
#define VSTR 2560

__global__ __launch_bounds__(256, 2) void fir_conv_mfma(
        const float* __restrict__ x,
        const ushort* __restrict__ wtab,
        const float* __restrict__ zi,
        float* __restrict__ y) {
    __shared__ ushort xe[VBM * VSTR / 2];
    const int t0 = blockIdx.x * VBT;
    const int i0 = blockIdx.y * VBM;
    const int tid = threadIdx.x;
    const int lane = tid & 63, wid = tid >> 6;
    const int l15 = lane & 15, lg = lane >> 4;

    short8 wf[18];
    #pragma unroll
    for (int a = 0; a < 18; ++a)
        wf[a] = *(const short8*)&wtab[((a + 2) * 64 + lane) * 8];

    #pragma unroll
    for (int it = 0; it < 8; ++it) {
        const int e = tid + it * 256;
        const int r = e >> 7;
        const int c8 = e & 127;
        const int g = t0 + c8 * 8;
        float4 v0 = *(const float4*)&x[(size_t)(i0 + r) * T_LEN + g];
        float4 v1 = *(const float4*)&x[(size_t)(i0 + r) * T_LEN + g + 4];
        short8 o;
        o[0] = (short)f2bf(v0.x); o[1] = (short)f2bf(v0.y);
        o[2] = (short)f2bf(v0.z); o[3] = (short)f2bf(v0.w);
        o[4] = (short)f2bf(v1.x); o[5] = (short)f2bf(v1.y);
        o[6] = (short)f2bf(v1.z); o[7] = (short)f2bf(v1.w);
        const int off = (512 + c8 * 16) ^ ((r & 7) << 4);
        *(short8*)((char*)xe + r * VSTR + off) = o;
    }
    #pragma unroll
    for (int it = 0; it < 2; ++it) {
        const int e = tid + it * 256;
        const int r = e >> 5;
        const int c8 = e & 31;
        const int g = t0 - 256 + c8 * 8;
        short8 o;
        if (g >= 0) {
            float4 v0 = *(const float4*)&x[(size_t)(i0 + r) * T_LEN + g];
            float4 v1 = *(const float4*)&x[(size_t)(i0 + r) * T_LEN + g + 4];
            o[0] = (short)f2bf(v0.x); o[1] = (short)f2bf(v0.y);
            o[2] = (short)f2bf(v0.z); o[3] = (short)f2bf(v0.w);
            o[4] = (short)f2bf(v1.x); o[5] = (short)f2bf(v1.y);
            o[6] = (short)f2bf(v1.z); o[7] = (short)f2bf(v1.w);
        } else {
            #pragma unroll
            for (int jj = 0; jj < 8; ++jj)
                o[jj] = (short)f2bf(zi[(size_t)(i0 + r) * N_TAPS + (-1 - g - jj)]);
        }
        const int off = (c8 * 16) ^ ((r & 7) << 4);
        *(short8*)((char*)xe + r * VSTR + off) = o;
    }
    __syncthreads();

    f32x4 acc[4][4];
    #pragma unroll
    for (int c4 = 0; c4 < 4; ++c4)
        #pragma unroll
        for (int n = 0; n < 4; ++n) acc[c4][n] = (f32x4){0.f, 0.f, 0.f, 0.f};

    const int chunk0 = wid * 4;
    #pragma unroll
    for (int ui = 0; ui < 10; ++ui) {
        #pragma unroll
        for (int c4 = 0; c4 < 4; ++c4) {
            const int colw = (chunk0 + c4) * 64 + ui * 32 + lg * 8;
            const int off = (colw * 2) ^ ((l15 & 7) << 4);
            short8 af = *(const short8*)((const char*)xe + l15 * VSTR + off);
            #pragma unroll
            for (int ncol = 0; ncol < 4; ++ncol) {
                const int a = ncol + 18 - 2 * ui;
                if (a >= 2 && a <= 19)
                    acc[c4][ncol] = __builtin_amdgcn_mfma_f32_16x16x32_bf16(
                        af, wf[a - 2], acc[c4][ncol], 0, 0, 0);
            }
        }
    }

    #pragma unroll
    for (int c4 = 0; c4 < 4; ++c4) {
        #pragma unroll
        for (int ncol = 0; ncol < 4; ++ncol) {
            const size_t tcol = (size_t)t0 + (chunk0 + c4) * 64 + ncol * 16 + l15;
            #pragma unroll
            for (int rg = 0; rg < 4; ++rg) {
                y[(size_t)(i0 + lg * 4 + rg) * T_LEN + tcol] = acc[c4][ncol][rg];
            }
        }
    }
}

// ---------------------------------------------------------------------------
extern "C" void kernel_launch(void* const* d_in, const int* in_sizes, int n_in,
                              void* d_out, int out_size, void* d_ws, size_t ws_size,
                              hipStream_t stream) {
    const float* x  = (const float*)d_in[0];
    const float* b  = (const float*)d_in[1];
    const float* z  = (const float*)d_in[2];
    float* y = (float*)d_out;

    char* ws = (char*)d_ws;
    float*  zi   = (float*)ws;                            // 4 MB
    ushort* zbf  = (ushort*)(ws + (4u << 20));            // 4 MB
    ushort* wtab = (ushort*)(ws + (8u << 20));            // 22.5 KB (reserve 64K)
    float*  part = (float*)(ws + (8u << 20) + (64u << 10));

    int kslices = 16;
    while (kslices > 1 &&
           (size_t)(8u << 20) + (64u << 10) + (size_t)kslices * (4u << 20) > ws_size)
        kslices >>= 1;

    fir_build_wtab<<<22, 64, 0, stream>>>(b, wtab);
    fir_cast_z<<<N_TAPS * T_LEN / (256 * 8), 256, 0, stream>>>(z, zbf);

    dim3 ggrid(B_ROWS / MT, kslices);                     // 32 x 16 = 512 blocks
    fir_zi_gemm<<<ggrid, 512, 0, stream>>>(x, zbf, part, kslices);

    fir_zi_reduce<<<B_ROWS * N_TAPS / 4 / 256, 256, 0, stream>>>(part, zi, kslices);

    dim3 cgrid(T_LEN / VBT, B_ROWS / VBM);                // 8 x 256
    fir_conv_mfma<<<cgrid, 256, 0, stream>>>(x, wtab, zi, y);
}

// Round 6
// 105.592 us; speedup vs baseline: 1.1351x; 1.1351x over previous
//
#include <hip/hip_runtime.h>
#include <hip/hip_bf16.h>

#define B_ROWS 4096
#define T_LEN  8192
#define N_TAPS 256

typedef __attribute__((ext_vector_type(8))) short short8;
typedef __attribute__((ext_vector_type(4))) short short4v;
typedef __attribute__((ext_vector_type(4))) float f32x4;

__device__ inline ushort f2bf(float f) {
    __hip_bfloat16 h = __float2bfloat16(f);
    union { __hip_bfloat16 h; ushort u; } c;
    c.h = h;
    return c.u;
}

// ---------------------------------------------------------------------------
// Phase 0a: cast z (256 x 8192 fp32) -> zbf (bf16)
// ---------------------------------------------------------------------------
__global__ __launch_bounds__(256) void fir_cast_z(const float* __restrict__ z,
                                                  ushort* __restrict__ zbf) {
    const int idx = (blockIdx.x * 256 + threadIdx.x) * 8;
    float4 a = *(const float4*)&z[idx];
    float4 b = *(const float4*)&z[idx + 4];
    short8 o;
    o[0] = (short)f2bf(a.x); o[1] = (short)f2bf(a.y);
    o[2] = (short)f2bf(a.z); o[3] = (short)f2bf(a.w);
    o[4] = (short)f2bf(b.x); o[5] = (short)f2bf(b.y);
    o[6] = (short)f2bf(b.z); o[7] = (short)f2bf(b.w);
    *(short8*)&zbf[idx] = o;
}

// ---------------------------------------------------------------------------
// Phase 0b: Toeplitz B-fragment table (unchanged, verified R3)
// ---------------------------------------------------------------------------
__global__ void fir_build_wtab(const float* __restrict__ b,
                               ushort* __restrict__ wtab) {
    const int a = blockIdx.x;        // 0..21
    const int lane = threadIdx.x;    // 0..63
    const int l15 = lane & 15, lg = lane >> 4;
    short8 o;
    #pragma unroll
    for (int j = 0; j < 8; ++j) {
        const int bi = 16 * a - 32 + l15 - lg * 8 - j;
        const float v = (bi >= 0 && bi < N_TAPS) ? b[bi] : 0.f;
        o[j] = (short)f2bf(v);
    }
    *(short8*)&wtab[(a * 64 + lane) * 8] = o;
}

// ---------------------------------------------------------------------------
// Phase 1: zi GEMM.
// Diagnosis R3-R5: the compiler serialized staging loads (one reg, 16x
// waitcnt/iter) under an occupancy-chasing register cap. Fix:
//  - __launch_bounds__(256, 2): ~256-reg headroom so all 12 staging loads
//    stay in flight (one vmcnt wait per iter, not 16)
//  - BM=64, 4 waves, grid (64, 8) = 512 blocks = 2 independent blocks/CU
//    (LDS 40 KB single-buffer) -> inter-block TLP hides residual stalls
//  - reg-carried prefetch: loads(t+1) issued right after regs(t) stored to
//    LDS; consumed next iter. Barriers never wait on in-flight prefetch.
// ---------------------------------------------------------------------------
#define MT 64
#define GBK 64

__global__ __launch_bounds__(256, 2) void fir_zi_gemm(
        const float* __restrict__ x,
        const ushort* __restrict__ zbf,
        float* __restrict__ part,
        int kslices) {
    __shared__ ushort As[MT * GBK];       // 8 KB
    __shared__ ushort Bs[N_TAPS * GBK];   // 32 KB
    const int i0 = blockIdx.x * MT;
    const int ks = blockIdx.y;
    const int klen = T_LEN / kslices;     // 1024
    const int kbase = ks * klen;
    const int tid = threadIdx.x;
    const int wn = tid >> 6;              // wave id = N-col block
    const int lane = tid & 63;
    const int l15 = lane & 15, lg = lane >> 4;

    // A staging: 4 rounds, e = tid + q*256: r = e>>4 (0..63), c4 = (e&15)*4
    const int a_r = tid >> 4;
    const int a_c4 = (tid & 15) * 4;
    // B staging: 8 rounds, e = tid + q*256: r = e>>3 (0..255), c8 = (e&7)*8
    const int b_r0 = tid >> 3;            // rows step +32 per round
    const int b_c8 = (tid & 7) * 8;

    f32x4 acc[4][4];
    #pragma unroll
    for (int mi = 0; mi < 4; ++mi)
        #pragma unroll
        for (int ni = 0; ni < 4; ++ni) acc[mi][ni] = (f32x4){0.f, 0.f, 0.f, 0.f};

    const int nt = klen / GBK;            // 16

    float4 apf[4];
    short8 bpf[8];

    auto loadT = [&](int kc) {
        #pragma unroll
        for (int q = 0; q < 4; ++q) {
            const int r = a_r;  // same row each round? no: rows 0..63 via e
            // e = tid + q*256 -> r = a_r + q*16
            apf[q] = *(const float4*)&x[(size_t)(i0 + a_r + q * 16) * T_LEN
                                        + kbase + kc + a_c4];
            (void)r;
        }
        #pragma unroll
        for (int q = 0; q < 8; ++q) {
            // e = tid + q*256 -> r = b_r0 + q*32
            bpf[q] = *(const short8*)&zbf[(size_t)(b_r0 + q * 32) * T_LEN
                                          + kbase + kc + b_c8];
        }
    };
    auto storeT = [&]() {
        #pragma unroll
        for (int q = 0; q < 4; ++q) {
            const int r = a_r + q * 16;
            short4v o;
            o[0] = (short)f2bf(apf[q].x); o[1] = (short)f2bf(apf[q].y);
            o[2] = (short)f2bf(apf[q].z); o[3] = (short)f2bf(apf[q].w);
            const int boff = r * 128 + ((a_c4 * 2) ^ ((r & 7) << 4));
            *(short4v*)((char*)As + boff) = o;
        }
        #pragma unroll
        for (int q = 0; q < 8; ++q) {
            const int r = b_r0 + q * 32;
            const int boff = r * 128 + ((b_c8 * 2) ^ ((r & 7) << 4));
            *(short8*)((char*)Bs + boff) = bpf[q];
        }
    };

    loadT(0);
    for (int t = 0; t < nt; ++t) {
        __syncthreads();          // LDS frags of iter t-1 fully consumed
        storeT();                 // waits vmcnt on loads(t), writes LDS
        if (t + 1 < nt) loadT((t + 1) * GBK);   // in flight across iter t
        __syncthreads();          // LDS tile t visible
        #pragma unroll
        for (int ksb = 0; ksb < 2; ++ksb) {
            short8 af[4], bfr[4];
            const int cb = (lg * 8 + ksb * 32) * 2;
            #pragma unroll
            for (int mi = 0; mi < 4; ++mi) {
                const int row = mi * 16 + l15;
                af[mi] = *(const short8*)((const char*)As + row * 128
                                          + (cb ^ ((row & 7) << 4)));
            }
            #pragma unroll
            for (int ni = 0; ni < 4; ++ni) {
                const int row = wn * 64 + ni * 16 + l15;
                bfr[ni] = *(const short8*)((const char*)Bs + row * 128
                                           + (cb ^ ((row & 7) << 4)));
            }
            #pragma unroll
            for (int mi = 0; mi < 4; ++mi)
                #pragma unroll
                for (int ni = 0; ni < 4; ++ni)
                    acc[mi][ni] = __builtin_amdgcn_mfma_f32_16x16x32_bf16(
                        af[mi], bfr[ni], acc[mi][ni], 0, 0, 0);
        }
    }

    // C/D layout: col = lane&15, row = (lane>>4)*4 + reg
    #pragma unroll
    for (int mi = 0; mi < 4; ++mi) {
        #pragma unroll
        for (int ni = 0; ni < 4; ++ni) {
            const int gn = wn * 64 + ni * 16 + l15;
            #pragma unroll
            for (int rg = 0; rg < 4; ++rg) {
                const int gm = i0 + mi * 16 + lg * 4 + rg;
                part[((size_t)ks * B_ROWS + gm) * N_TAPS + gn] = acc[mi][ni][rg];
            }
        }
    }
}

// ---------------------------------------------------------------------------
// Phase 2: reduce split-K partials -> zi
// ---------------------------------------------------------------------------
__global__ __launch_bounds__(256) void fir_zi_reduce(const float* __restrict__ part,
                                                     float* __restrict__ zi,
                                                     int kslices) {
    const int idx = blockIdx.x * 256 + threadIdx.x;
    const int total = B_ROWS * N_TAPS / 4;
    if (idx >= total) return;
    float4 s = ((const float4*)part)[idx];
    for (int q = 1; q < kslices; ++q) {
        float4 v = ((const float4*)part)[(size_t)q * total + idx];
        s.x += v.x; s.y += v.y; s.z += v.z; s.w += v.w;
    }
    ((float4*)zi)[idx] = s;
}

// ---------------------------------------------------------------------------
// Phase 3: FIR conv via MFMA (unchanged from R3 — verified)
// ---------------------------------------------------------------------------
#define VBM 16
#define VBT 1024
#define VWIN 1280
#define VSTR 2560

__global__ __launch_bounds__(256, 2) void fir_conv_mfma(
        const float* __restrict__ x,
        const ushort* __restrict__ wtab,
        const float* __restrict__ zi,
        float* __restrict__ y) {
    __shared__ ushort xe[VBM * VSTR / 2];
    const int t0 = blockIdx.x * VBT;
    const int i0 = blockIdx.y * VBM;
    const int tid = threadIdx.x;
    const int lane = tid & 63, wid = tid >> 6;
    const int l15 = lane & 15, lg = lane >> 4;

    short8 wf[18];
    #pragma unroll
    for (int a = 0; a < 18; ++a)
        wf[a] = *(const short8*)&wtab[((a + 2) * 64 + lane) * 8];

    #pragma unroll
    for (int it = 0; it < 8; ++it) {
        const int e = tid + it * 256;
        const int r = e >> 7;
        const int c8 = e & 127;
        const int g = t0 + c8 * 8;
        float4 v0 = *(const float4*)&x[(size_t)(i0 + r) * T_LEN + g];
        float4 v1 = *(const float4*)&x[(size_t)(i0 + r) * T_LEN + g + 4];
        short8 o;
        o[0] = (short)f2bf(v0.x); o[1] = (short)f2bf(v0.y);
        o[2] = (short)f2bf(v0.z); o[3] = (short)f2bf(v0.w);
        o[4] = (short)f2bf(v1.x); o[5] = (short)f2bf(v1.y);
        o[6] = (short)f2bf(v1.z); o[7] = (short)f2bf(v1.w);
        const int off = (512 + c8 * 16) ^ ((r & 7) << 4);
        *(short8*)((char*)xe + r * VSTR + off) = o;
    }
    #pragma unroll
    for (int it = 0; it < 2; ++it) {
        const int e = tid + it * 256;
        const int r = e >> 5;
        const int c8 = e & 31;
        const int g = t0 - 256 + c8 * 8;
        short8 o;
        if (g >= 0) {
            float4 v0 = *(const float4*)&x[(size_t)(i0 + r) * T_LEN + g];
            float4 v1 = *(const float4*)&x[(size_t)(i0 + r) * T_LEN + g + 4];
            o[0] = (short)f2bf(v0.x); o[1] = (short)f2bf(v0.y);
            o[2] = (short)f2bf(v0.z); o[3] = (short)f2bf(v0.w);
            o[4] = (short)f2bf(v1.x); o[5] = (short)f2bf(v1.y);
            o[6] = (short)f2bf(v1.z); o[7] = (short)f2bf(v1.w);
        } else {
            #pragma unroll
            for (int jj = 0; jj < 8; ++jj)
                o[jj] = (short)f2bf(zi[(size_t)(i0 + r) * N_TAPS + (-1 - g - jj)]);
        }
        const int off = (c8 * 16) ^ ((r & 7) << 4);
        *(short8*)((char*)xe + r * VSTR + off) = o;
    }
    __syncthreads();

    f32x4 acc[4][4];
    #pragma unroll
    for (int c4 = 0; c4 < 4; ++c4)
        #pragma unroll
        for (int n = 0; n < 4; ++n) acc[c4][n] = (f32x4){0.f, 0.f, 0.f, 0.f};

    const int chunk0 = wid * 4;
    #pragma unroll
    for (int ui = 0; ui < 10; ++ui) {
        #pragma unroll
        for (int c4 = 0; c4 < 4; ++c4) {
            const int colw = (chunk0 + c4) * 64 + ui * 32 + lg * 8;
            const int off = (colw * 2) ^ ((l15 & 7) << 4);
            short8 af = *(const short8*)((const char*)xe + l15 * VSTR + off);
            #pragma unroll
            for (int ncol = 0; ncol < 4; ++ncol) {
                const int a = ncol + 18 - 2 * ui;
                if (a >= 2 && a <= 19)
                    acc[c4][ncol] = __builtin_amdgcn_mfma_f32_16x16x32_bf16(
                        af, wf[a - 2], acc[c4][ncol], 0, 0, 0);
            }
        }
    }

    #pragma unroll
    for (int c4 = 0; c4 < 4; ++c4) {
        #pragma unroll
        for (int ncol = 0; ncol < 4; ++ncol) {
            const size_t tcol = (size_t)t0 + (chunk0 + c4) * 64 + ncol * 16 + l15;
            #pragma unroll
            for (int rg = 0; rg < 4; ++rg) {
                y[(size_t)(i0 + lg * 4 + rg) * T_LEN + tcol] = acc[c4][ncol][rg];
            }
        }
    }
}

// ---------------------------------------------------------------------------
extern "C" void kernel_launch(void* const* d_in, const int* in_sizes, int n_in,
                              void* d_out, int out_size, void* d_ws, size_t ws_size,
                              hipStream_t stream) {
    const float* x  = (const float*)d_in[0];
    const float* b  = (const float*)d_in[1];
    const float* z  = (const float*)d_in[2];
    float* y = (float*)d_out;

    char* ws = (char*)d_ws;
    float*  zi   = (float*)ws;                            // 4 MB
    ushort* zbf  = (ushort*)(ws + (4u << 20));            // 4 MB
    ushort* wtab = (ushort*)(ws + (8u << 20));            // 22.5 KB (reserve 64K)
    float*  part = (float*)(ws + (8u << 20) + (64u << 10));

    int kslices = 8;
    while (kslices > 1 &&
           (size_t)(8u << 20) + (64u << 10) + (size_t)kslices * (4u << 20) > ws_size)
        kslices >>= 1;

    fir_build_wtab<<<22, 64, 0, stream>>>(b, wtab);
    fir_cast_z<<<N_TAPS * T_LEN / (256 * 8), 256, 0, stream>>>(z, zbf);

    dim3 ggrid(B_ROWS / MT, kslices);                     // 64 x 8 = 512 blocks
    fir_zi_gemm<<<ggrid, 256, 0, stream>>>(x, zbf, part, kslices);

    fir_zi_reduce<<<B_ROWS * N_TAPS / 4 / 256, 256, 0, stream>>>(part, zi, kslices);

    dim3 cgrid(T_LEN / VBT, B_ROWS / VBM);                // 8 x 256
    fir_conv_mfma<<<cgrid, 256, 0, stream>>>(x, wtab, zi, y);
}